// Round 5
// baseline (592.279 us; speedup 1.0000x reference)
//
#include <hip/hip_runtime.h>

#define BATCH 65536
#define DIM 128
#define NPROTO 512
#define ODIM 8

// ---------------- prep: w[p][d] = proto[p][d] * rel[d]^2 ; psq[p] = sum_d rel^2 * proto^2
__global__ void grlvq_prep(const float* __restrict__ proto,
                           const float* __restrict__ rel,
                           float* __restrict__ w,
                           float* __restrict__ psq) {
    int p = blockIdx.x * blockDim.x + threadIdx.x;
    if (p >= NPROTO) return;
    float acc = 0.f;
    #pragma unroll 8
    for (int d = 0; d < DIM; ++d) {
        float r = rel[d];
        float r2 = r * r;
        float v = proto[p * DIM + d];
        w[p * DIM + d] = v * r2;
        acc = fmaf(r2 * v, v, acc);
    }
    psq[p] = acc;
}

// ---------------- main: thread-per-row argmin over prototypes, fp32 VALU
__global__ __launch_bounds__(256) void grlvq_main(const float* __restrict__ x,
                                                  const float* __restrict__ w,
                                                  const float* __restrict__ psq,
                                                  const float* __restrict__ pout,
                                                  float* __restrict__ out) {
    const int b = blockIdx.x * 256 + threadIdx.x;

    // load my row into registers (32 x float4 = 128 VGPRs)
    const float4* xp = (const float4*)(x + (size_t)b * DIM);
    float4 xr[32];
    #pragma unroll
    for (int i = 0; i < 32; ++i) xr[i] = xp[i];

    float best = INFINITY;
    int bestIdx = 0;

    for (int p0 = 0; p0 < NPROTO; p0 += 8) {
        float acc[8];
        #pragma unroll
        for (int j = 0; j < 8; ++j) acc[j] = 0.f;

        const float* wbase = w + (size_t)p0 * DIM;
        #pragma unroll
        for (int i = 0; i < 32; ++i) {
            float4 xv = xr[i];
            #pragma unroll
            for (int j = 0; j < 8; ++j) {
                // wave-uniform address -> scalar (s_load) reads, SGPR operand to v_fmac
                float4 wv = *(const float4*)(wbase + (size_t)j * DIM + i * 4);
                acc[j] = fmaf(xv.x, wv.x, acc[j]);
                acc[j] = fmaf(xv.y, wv.y, acc[j]);
                acc[j] = fmaf(xv.z, wv.z, acc[j]);
                acc[j] = fmaf(xv.w, wv.w, acc[j]);
            }
        }

        #pragma unroll
        for (int j = 0; j < 8; ++j) {
            float s = psq[p0 + j] - 2.0f * acc[j];
            if (s < best) { best = s; bestIdx = p0 + j; }  // strict < => first-min (jnp.argmin tie rule)
        }
    }

    // gather the 8-float output row of the winning prototype
    const float4* po = (const float4*)(pout + (size_t)bestIdx * ODIM);
    float4* op = (float4*)(out + (size_t)b * ODIM);
    op[0] = po[0];
    op[1] = po[1];
}

extern "C" void kernel_launch(void* const* d_in, const int* in_sizes, int n_in,
                              void* d_out, int out_size, void* d_ws, size_t ws_size,
                              hipStream_t stream) {
    const float* x     = (const float*)d_in[0];  // [BATCH, DIM]
    const float* proto = (const float*)d_in[1];  // [NPROTO, DIM]
    const float* pout  = (const float*)d_in[2];  // [NPROTO, ODIM]
    const float* rel   = (const float*)d_in[3];  // [DIM]
    float* out = (float*)d_out;                  // [BATCH, ODIM]

    float* w   = (float*)d_ws;                   // NPROTO*DIM floats
    float* psq = w + NPROTO * DIM;               // NPROTO floats

    grlvq_prep<<<(NPROTO + 255) / 256, 256, 0, stream>>>(proto, rel, w, psq);
    grlvq_main<<<BATCH / 256, 256, 0, stream>>>(x, w, psq, pout, out);
}

// Round 6
// 267.000 us; speedup vs baseline: 2.2183x; 2.2183x over previous
//
#include <hip/hip_runtime.h>

#define BATCH 65536
#define DIM 128
#define NPROTO 512
#define ODIM 8
#define CHUNKS 8
#define PPC (NPROTO / CHUNKS)   // 64 prototypes per chunk

// ---------------- prep: w[p][d] = proto[p][d] * rel[d]^2 ; psq[p] = sum_d rel^2 * proto^2
__global__ void grlvq_prep(const float* __restrict__ proto,
                           const float* __restrict__ rel,
                           float* __restrict__ w,
                           float* __restrict__ psq) {
    int p = blockIdx.x * blockDim.x + threadIdx.x;
    if (p >= NPROTO) return;
    float acc = 0.f;
    #pragma unroll 8
    for (int d = 0; d < DIM; ++d) {
        float r = rel[d];
        float r2 = r * r;
        float v = proto[p * DIM + d];
        w[p * DIM + d] = v * r2;
        acc = fmaf(r2 * v, v, acc);
    }
    psq[p] = acc;
}

// ---------------- chunk kernel: each thread handles one row x one 64-proto chunk
__global__ __launch_bounds__(256) void grlvq_chunk(const float* __restrict__ x,
                                                   const float* __restrict__ w,
                                                   const float* __restrict__ psq,
                                                   float* __restrict__ score,
                                                   int* __restrict__ sidx) {
    const int b = blockIdx.x * 256 + threadIdx.x;
    const int chunk = blockIdx.y;
    const int pbase = chunk * PPC;

    const float4* xp = (const float4*)(x + (size_t)b * DIM);
    float4 xr[32];
    #pragma unroll
    for (int i = 0; i < 32; ++i) xr[i] = xp[i];

    float best = INFINITY;
    int bestIdx = pbase;

    for (int p0 = pbase; p0 < pbase + PPC; p0 += 8) {
        float2 acc[8];
        #pragma unroll
        for (int j = 0; j < 8; ++j) acc[j] = make_float2(0.f, 0.f);

        const float* wbase = w + (size_t)p0 * DIM;
        #pragma unroll
        for (int i = 0; i < 32; ++i) {
            float4 xv = xr[i];
            #pragma unroll
            for (int j = 0; j < 8; ++j) {
                // wave-uniform address -> scalar s_load, SGPR operand to FMA
                float4 wv = *(const float4*)(wbase + (size_t)j * DIM + i * 4);
                acc[j].x = fmaf(xv.x, wv.x, acc[j].x);
                acc[j].y = fmaf(xv.y, wv.y, acc[j].y);
                acc[j].x = fmaf(xv.z, wv.z, acc[j].x);
                acc[j].y = fmaf(xv.w, wv.w, acc[j].y);
            }
        }

        #pragma unroll
        for (int j = 0; j < 8; ++j) {
            float s = psq[p0 + j] - 2.0f * (acc[j].x + acc[j].y);
            if (s < best) { best = s; bestIdx = p0 + j; }  // strict < => first-min
        }
    }

    score[(size_t)b * CHUNKS + chunk] = best;
    sidx [(size_t)b * CHUNKS + chunk] = bestIdx;
}

// ---------------- reduce + gather: pick global min over 8 chunk candidates
__global__ __launch_bounds__(256) void grlvq_reduce(const float* __restrict__ score,
                                                    const int* __restrict__ sidx,
                                                    const float* __restrict__ pout,
                                                    float* __restrict__ out) {
    const int b = blockIdx.x * 256 + threadIdx.x;
    float best = INFINITY;
    int bi = 0;
    #pragma unroll
    for (int c = 0; c < CHUNKS; ++c) {   // ascending chunk = ascending proto idx => first-min ties
        float s = score[(size_t)b * CHUNKS + c];
        int id = sidx[(size_t)b * CHUNKS + c];
        if (s < best) { best = s; bi = id; }
    }
    const float4* po = (const float4*)(pout + (size_t)bi * ODIM);
    float4* op = (float4*)(out + (size_t)b * ODIM);
    op[0] = po[0];
    op[1] = po[1];
}

extern "C" void kernel_launch(void* const* d_in, const int* in_sizes, int n_in,
                              void* d_out, int out_size, void* d_ws, size_t ws_size,
                              hipStream_t stream) {
    const float* x     = (const float*)d_in[0];  // [BATCH, DIM]
    const float* proto = (const float*)d_in[1];  // [NPROTO, DIM]
    const float* pout  = (const float*)d_in[2];  // [NPROTO, ODIM]
    const float* rel   = (const float*)d_in[3];  // [DIM]
    float* out = (float*)d_out;                  // [BATCH, ODIM]

    float* w     = (float*)d_ws;                 // NPROTO*DIM floats      (256 KB)
    float* psq   = w + NPROTO * DIM;             // NPROTO floats
    float* score = psq + NPROTO;                 // BATCH*CHUNKS floats    (2 MB)
    int*   sidx  = (int*)(score + (size_t)BATCH * CHUNKS); // BATCH*CHUNKS ints (2 MB)

    grlvq_prep<<<(NPROTO + 255) / 256, 256, 0, stream>>>(proto, rel, w, psq);
    grlvq_chunk<<<dim3(BATCH / 256, CHUNKS), 256, 0, stream>>>(x, w, psq, score, sidx);
    grlvq_reduce<<<BATCH / 256, 256, 0, stream>>>(score, sidx, pout, out);
}